// Round 16
// baseline (397.156 us; speedup 1.0000x reference)
//
#include <hip/hip_runtime.h>

#define B_ 64
#define T_ 256
#define DIN_ 1024
#define DOUT_ 1024

typedef int v4i  __attribute__((ext_vector_type(4)));
typedef int v16i __attribute__((ext_vector_type(16)));

#define PRE_BYTES 134217728ULL   // 256*1024*64*8
#define XS_BYTES  83886080ULL    // 5*256*32*2*1024
#define WSL_BYTES 5242880ULL     // 5*32*32*1024
#define SPM_BYTES 2097152ULL     // 256*1024*8

// async 16B/lane global->LDS DMA: lane i's 16 B from g+i*16 land at l+i*16.
__device__ __forceinline__ void async_copy16(const void* g, void* l) {
    __builtin_amdgcn_global_load_lds(
        (const __attribute__((address_space(1))) void*)g,
        (__attribute__((address_space(3))) void*)l, 16, 0, 0);
}

// -----------------------------------------------------------------------------
// Split x into 5 signed-i8 slices, fixed scale 2^3, MFMA A-frag chunk order:
// chunk(s,t,kt,mt) = 1KB, byte = lane*16+j, lane = kh*32+m,
// element = x[b=mt*32+m][t][kt*32+kh*16+j]. 5 slices = 34 bits >= fp32's 24;
// residual <= 2^-32 absolute.
// -----------------------------------------------------------------------------
__global__ __launch_bounds__(256) void snn_split_x(
    const float* __restrict__ x, char* __restrict__ xs)
{
    const int W    = blockIdx.x * 4 + (threadIdx.x >> 6);   // 0..16383
    const int lane = threadIdx.x & 63;
    const int mt = W & 1, kt = (W >> 1) & 31, t0 = W >> 6;
    const int m = lane & 31, kh = lane >> 5;
    const int b = mt * 32 + m;

    const float* src = x + ((size_t)b * T_ + t0) * DIN_ + kt * 32 + kh * 16;
    float f[16];
    *(float4*)(f)      = *(const float4*)(src);
    *(float4*)(f + 4)  = *(const float4*)(src + 4);
    *(float4*)(f + 8)  = *(const float4*)(src + 8);
    *(float4*)(f + 12) = *(const float4*)(src + 12);

    unsigned pk[5][4];
#pragma unroll
    for (int s = 0; s < 5; ++s)
        pk[s][0] = pk[s][1] = pk[s][2] = pk[s][3] = 0u;
#pragma unroll
    for (int j = 0; j < 16; ++j) {
        float v = f[j] * 0.125f;                 // / 2^3 (exact)
#pragma unroll
        for (int s = 0; s < 5; ++s) {
            const float ml = (s == 0) ? 64.f : 128.f;
            const float sv = __builtin_rintf(v * ml);
            v = v * ml - sv;                     // exact residual
            const int iv = (int)sv;
            pk[s][j >> 2] |= ((unsigned)iv & 0xffu) << ((j & 3) * 8);
        }
    }
#pragma unroll
    for (int s = 0; s < 5; ++s) {
        char* dst = xs + (size_t)(((s * 256 + t0) * 32 + kt) * 2 + mt) * 1024
                       + lane * 16;
        *(uint4*)dst = make_uint4(pk[s][0], pk[s][1], pk[s][2], pk[s][3]);
    }
}

// -----------------------------------------------------------------------------
// Split W into 5 i8 slices, fixed scale 2^-2, B-frag chunk order:
// chunk(s,ot,kt) = 1KB, element = W[o=ot*32+n][kt*32+kh*16+j].
// -----------------------------------------------------------------------------
__global__ __launch_bounds__(256) void snn_split_w(
    const float* __restrict__ Wt, char* __restrict__ wsl)
{
    const int W    = blockIdx.x * 4 + (threadIdx.x >> 6);   // 0..1023
    const int lane = threadIdx.x & 63;
    const int kt = W & 31, ot = W >> 5;
    const int n = lane & 31, kh = lane >> 5;
    const int o = ot * 32 + n;

    const float* src = Wt + (size_t)o * DIN_ + kt * 32 + kh * 16;
    float f[16];
    *(float4*)(f)      = *(const float4*)(src);
    *(float4*)(f + 4)  = *(const float4*)(src + 4);
    *(float4*)(f + 8)  = *(const float4*)(src + 8);
    *(float4*)(f + 12) = *(const float4*)(src + 12);

    unsigned pk[5][4];
#pragma unroll
    for (int s = 0; s < 5; ++s)
        pk[s][0] = pk[s][1] = pk[s][2] = pk[s][3] = 0u;
#pragma unroll
    for (int j = 0; j < 16; ++j) {
        float v = f[j] * 4.0f;                   // / 2^-2 (exact)
#pragma unroll
        for (int s = 0; s < 5; ++s) {
            const float ml = (s == 0) ? 64.f : 128.f;
            const float sv = __builtin_rintf(v * ml);
            v = v * ml - sv;
            const int iv = (int)sv;
            pk[s][j >> 2] |= ((unsigned)iv & 0xffu) << ((j & 3) * 8);
        }
    }
#pragma unroll
    for (int s = 0; s < 5; ++s) {
        char* dst = wsl + (size_t)((s * 32 + ot) * 32 + kt) * 1024 + lane * 16;
        *(uint4*)dst = make_uint4(pk[s][0], pk[s][1], pk[s][2], pk[s][3]);
    }
}

// -----------------------------------------------------------------------------
// GEMM via i8 MFMA — 3-stage DMA ring pipeline (hipBLASLt-style).
// Block (t0, oB) = 64b x 64o, 4 waves 2x2; each wave DMA-stages 5 chunks/kt
// and computes 15 exact pair-MFMAs/kt.  Per stage:
//   s_waitcnt vmcnt(5)   (drain own kt-chunks; kt+1/kt+2 stay in flight)
//   s_barrier            (raw -- cross-wave: every wave drained ITS kt chunks)
//   DMA kt+2 -> ring buffer (kt+2)%3   (two full compute intervals to land)
//   ds_read kt fragments, MFMA.
// Three SEPARATE __shared__ arrays keep alias analysis per-object.
// i32 accumulation -> bit-exact regardless of schedule.
// -----------------------------------------------------------------------------
__global__ __launch_bounds__(256, 2) void snn_gemm_i8(
    const char* __restrict__ xs, const char* __restrict__ wsl,
    const float* __restrict__ bias, double* __restrict__ pre)
{
    __shared__ __align__(16) char ldsA[20 * 1024];
    __shared__ __align__(16) char ldsB[20 * 1024];
    __shared__ __align__(16) char ldsC[20 * 1024];

    const int t0 = blockIdx.x >> 4;          // A-reuse: adjacent blocks share t0
    const int oB = blockIdx.x & 15;
    const int tid = threadIdx.x;
    const int lane = tid & 63;
    const int ws = __builtin_amdgcn_readfirstlane(tid >> 6);   // scalar wave id
    const int wm5 = (ws >> 1) * 5;           // A fragment chunk base
    const int wo5 = 10 + (ws & 1) * 5;       // B fragment chunk base

    v16i zero;
#pragma unroll
    for (int r = 0; r < 16; ++r) zero[r] = 0;
    v16i acc[5];
#pragma unroll
    for (int g = 0; g < 5; ++g) acc[g] = zero;

    // DMA sources: waves 0,1 stage A (mt = ws), waves 2,3 stage B (ot = ws-2).
    const char* gsrc;
    size_t sStride;
    int ktStride, slot0;
    if (ws < 2) {
        gsrc    = xs + ((size_t)t0 * 32 * 2 + ws) * 1024;
        sStride = 16777216;                                    // 256*32*2*1024
        ktStride = 2048;
        slot0 = ws * 5;
    } else {
        gsrc    = wsl + (size_t)(oB * 2 + (ws - 2)) * 32 * 1024;
        sStride = 1048576;                                     // 32*32*1024
        ktStride = 1024;
        slot0 = 10 + (ws - 2) * 5;
    }
    const int lo = lane * 16;

#define DMA_KT(BUF, ktv)                                                     \
    {                                                                        \
        const char* g_ = gsrc + (size_t)(ktv) * ktStride;                    \
        _Pragma("unroll")                                                    \
        for (int s_ = 0; s_ < 5; ++s_)                                       \
            async_copy16(g_ + (size_t)s_ * sStride + lo,                     \
                         &BUF[(slot0 + s_) * 1024]);                         \
    }

#define COMPUTE_KT(BUF)                                                      \
    {                                                                        \
        v4i a_[5], b_[5];                                                    \
        _Pragma("unroll")                                                    \
        for (int s_ = 0; s_ < 5; ++s_) {                                     \
            a_[s_] = *(const v4i*)(&BUF[(wm5 + s_) * 1024] + lo);            \
            b_[s_] = *(const v4i*)(&BUF[(wo5 + s_) * 1024] + lo);            \
        }                                                                    \
        _Pragma("unroll")                                                    \
        for (int i_ = 0; i_ < 5; ++i_) {                                     \
            _Pragma("unroll")                                                \
            for (int j_ = 0; j_ < 5 - i_; ++j_)                              \
                acc[i_ + j_] = __builtin_amdgcn_mfma_i32_32x32x32_i8(        \
                    a_[i_], b_[j_], acc[i_ + j_], 0, 0, 0);                  \
        }                                                                    \
    }

#define STAGE(RBUF, WBUF, ktv)                                               \
    {                                                                        \
        asm volatile("s_waitcnt vmcnt(5)" ::: "memory");                     \
        __builtin_amdgcn_s_barrier();                                        \
        DMA_KT(WBUF, (ktv) + 2);                                             \
        COMPUTE_KT(RBUF);                                                    \
    }

    // prologue: kt=0 -> ldsA, kt=1 -> ldsB
    DMA_KT(ldsA, 0);
    DMA_KT(ldsB, 1);

    // stages 0..29 (each iteration covers kt, kt+1, kt+2; DMAs for kt+2..kt+4)
    for (int kt = 0; kt < 28; kt += 3) {
        STAGE(ldsA, ldsC, kt);       // read kt%3==0, write (kt+2)%3==2
        STAGE(ldsB, ldsA, kt + 1);
        STAGE(ldsC, ldsB, kt + 2);
    }
    // peeled tails: kt=30 (buf 0), kt=31 (buf 1); no more DMA
    {
        asm volatile("s_waitcnt vmcnt(5)" ::: "memory");
        __builtin_amdgcn_s_barrier();
        COMPUTE_KT(ldsA);
    }
    {
        asm volatile("s_waitcnt vmcnt(0)" ::: "memory");
        __builtin_amdgcn_s_barrier();
        COMPUTE_KT(ldsB);
    }
#undef STAGE
#undef COMPUTE_KT
#undef DMA_KT

    // epilogue: D layout col=lane&31 (o), row=(r&3)+8*(r>>2)+4*(lane>>5) (b)
    const int n = lane & 31, lh = lane >> 5;
    const int o = oB * 64 + (ws & 1) * 32 + n;
    const double bv = (double)bias[o];
    double* dst = pre + ((size_t)t0 * DOUT_ + o) * 64 + (ws >> 1) * 32;
#pragma unroll
    for (int r = 0; r < 16; ++r) {
        const int row = (r & 3) + 8 * (r >> 2) + 4 * lh;
        double v = (double)acc[4][r];
        v = v * 0.0078125 + (double)acc[3][r];
        v = v * 0.0078125 + (double)acc[2][r];
        v = v * 0.0078125 + (double)acc[1][r];
        v = v * 0.0078125 + (double)acc[0][r];
        dst[row] = v * 0x1p-11 + bv;             // 2^{3-2-12}
    }
}

// -----------------------------------------------------------------------------
// Fallback GEMM (round-8 proven fp64-VALU path), used when ws is small.
// -----------------------------------------------------------------------------
__global__ __launch_bounds__(256, 2) void snn_gemm_fb(
    const float* __restrict__ x, const float* __restrict__ W,
    const float* __restrict__ bias, double* __restrict__ pre)
{
    __shared__ float smem[2][8 * 72 + 8 * 256];
    const int t0 = blockIdx.x & 255;
    const int o0 = blockIdx.x >> 8;
    const int tid = threadIdx.x;
    const int to = tid & 31;
    const int tb = tid >> 5;

    double acc[8][8];
#pragma unroll
    for (int i = 0; i < 8; ++i)
#pragma unroll
        for (int j = 0; j < 8; ++j) acc[i][j] = 0.0;

    const int arow = tid >> 2;
    const int ak2  = (tid & 3) * 2;
    const float* xg = x + (size_t)(t0 + 256 * arow) * DIN_ + ak2;
    const float* wg = W + (size_t)(o0 * 256 + tid) * DIN_;

    float2 f2  = *(const float2*)(xg);
    float4 bq0 = *(const float4*)(wg);
    float4 bq1 = *(const float4*)(wg + 4);

    for (int kc = 0; kc < DIN_ / 8; ++kc) {
        float* base = smem[kc & 1];
        float (*AsF)[72]  = (float(*)[72])base;
        float (*BsF)[256] = (float(*)[256])(base + 8 * 72);
        AsF[ak2 + 0][arow] = f2.x;
        AsF[ak2 + 1][arow] = f2.y;
        BsF[0][tid] = bq0.x;  BsF[1][tid] = bq0.y;
        BsF[2][tid] = bq0.z;  BsF[3][tid] = bq0.w;
        BsF[4][tid] = bq1.x;  BsF[5][tid] = bq1.y;
        BsF[6][tid] = bq1.z;  BsF[7][tid] = bq1.w;
        __syncthreads();
        if (kc + 1 < DIN_ / 8) {
            f2  = *(const float2*)(xg + (kc + 1) * 8);
            bq0 = *(const float4*)(wg + (kc + 1) * 8);
            bq1 = *(const float4*)(wg + (kc + 1) * 8 + 4);
        }
#pragma unroll
        for (int k = 0; k < 8; ++k) {
            const float4 af0 = *(const float4*)&AsF[k][tb * 8];
            const float4 af1 = *(const float4*)&AsF[k][tb * 8 + 4];
            const float4 bf0 = *(const float4*)&BsF[k][to * 4];
            const float4 bf1 = *(const float4*)&BsF[k][128 + to * 4];
            double a[8], b[8];
            a[0] = (double)af0.x; a[1] = (double)af0.y;
            a[2] = (double)af0.z; a[3] = (double)af0.w;
            a[4] = (double)af1.x; a[5] = (double)af1.y;
            a[6] = (double)af1.z; a[7] = (double)af1.w;
            b[0] = (double)bf0.x; b[1] = (double)bf0.y;
            b[2] = (double)bf0.z; b[3] = (double)bf0.w;
            b[4] = (double)bf1.x; b[5] = (double)bf1.y;
            b[6] = (double)bf1.z; b[7] = (double)bf1.w;
#pragma unroll
            for (int i = 0; i < 8; ++i)
#pragma unroll
                for (int j = 0; j < 8; ++j)
                    acc[i][j] += a[i] * b[j];
        }
    }

    double biasd[8];
#pragma unroll
    for (int j = 0; j < 8; ++j)
        biasd[j] = (double)bias[o0 * 256 + (j >> 2) * 128 + to * 4 + (j & 3)];
    double (*trans)[67] = (double(*)[67])smem[0];
    for (int c = 0; c < 16; ++c) {
        __syncthreads();
        const int j4  = c >> 3;
        const int tlo = (c & 7) * 4;
        if (to >= tlo && to < tlo + 4) {
#pragma unroll
            for (int p4 = 0; p4 < 4; ++p4) {
                const int r = (to - tlo) * 4 + p4;
                const int j = j4 * 4 + p4;
#pragma unroll
                for (int i = 0; i < 8; ++i)
                    trans[r][tb * 8 + i] = acc[i][j] + biasd[j];
            }
        }
        __syncthreads();
#pragma unroll
        for (int q = 0; q < 4; ++q) {
            const int idx = tid + 256 * q;
            const int b  = idx & 63;
            const int oc = idx >> 6;
            pre[(size_t)(t0 * DOUT_ + o0 * 256 + c * 16 + oc) * 64 + b] = trans[oc][b];
        }
    }
}

// -----------------------------------------------------------------------------
// Scan: one wave per o, lane = b. Batch-mean via ballot+popcount.
// 16-deep load grouping (~8 MB in flight across 1024 waves) for HBM overlap.
// -----------------------------------------------------------------------------
__global__ __launch_bounds__(256) void snn_scan(
    const double* __restrict__ pre, const float* __restrict__ thr_in,
    unsigned long long* __restrict__ spM, float* __restrict__ outD)
{
    const int wid  = (blockIdx.x * blockDim.x + threadIdx.x) >> 6;
    const int lane = threadIdx.x & 63;
    if (wid >= DOUT_) return;
    const int o = wid;

    double mem = 0.0;
    double thr = (double)thr_in[o];
    const double* p = pre + (size_t)o * 64 + lane;

    for (int t = 0; t < T_; t += 16) {
        double pv[16];
#pragma unroll
        for (int j = 0; j < 16; ++j)
            pv[j] = p[(size_t)(t + j) * (DOUT_ * 64)];
#pragma unroll
        for (int j = 0; j < 16; ++j) {
            mem += pv[j];
            const bool s = (mem >= thr);
            const unsigned long long msk = __ballot(s);
            const int cnt = __popcll(msk);
            thr += 0.05 * ((double)cnt * (1.0 / 64.0) - 0.5);
            if (spM) {
                if (lane == 0) spM[(size_t)(t + j) * DOUT_ + o] = msk;
            } else {
                outD[(size_t)lane * (T_ * DOUT_) + (size_t)(t + j) * DOUT_ + o] =
                    s ? 1.0f : 0.0f;
            }
            mem = s ? 0.0 : mem;
        }
    }
}

__global__ __launch_bounds__(256) void snn_expand(
    const unsigned long long* __restrict__ spM, float* __restrict__ out)
{
    const int r = blockIdx.x * 256 + threadIdx.x;
    const unsigned long long m = spM[r];
#pragma unroll
    for (int b = 0; b < 64; ++b)
        out[(size_t)b * (T_ * DOUT_) + r] = (float)((m >> b) & 1ULL);
}

extern "C" void kernel_launch(void* const* d_in, const int* in_sizes, int n_in,
                              void* d_out, int out_size, void* d_ws, size_t ws_size,
                              hipStream_t stream) {
    const float* x    = (const float*)d_in[0];   // [64][256][1024]
    const float* W    = (const float*)d_in[1];   // [1024][1024]
    const float* bias = (const float*)d_in[2];   // [1024]
    const float* thr  = (const float*)d_in[3];   // [1024]
    float* out = (float*)d_out;                  // [64][256][1024]

    double* pre = (double*)d_ws;
    const size_t need = PRE_BYTES + XS_BYTES + WSL_BYTES + SPM_BYTES;

    if (ws_size >= need) {
        char* xs  = (char*)d_ws + PRE_BYTES;
        char* wsl = xs + XS_BYTES;
        unsigned long long* spM = (unsigned long long*)(wsl + WSL_BYTES);
        snn_split_x<<<4096, 256, 0, stream>>>(x, xs);
        snn_split_w<<<256, 256, 0, stream>>>(W, wsl);
        snn_gemm_i8<<<4096, 256, 0, stream>>>(xs, wsl, bias, pre);
        snn_scan<<<256, 256, 0, stream>>>(pre, thr, spM, nullptr);
        snn_expand<<<1024, 256, 0, stream>>>(spM, out);
    } else {
        const bool two_stage = (ws_size >= PRE_BYTES + SPM_BYTES);
        unsigned long long* spM =
            two_stage ? (unsigned long long*)((char*)d_ws + PRE_BYTES) : nullptr;
        snn_gemm_fb<<<1024, 256, 0, stream>>>(x, W, bias, pre);
        snn_scan<<<256, 256, 0, stream>>>(pre, thr, spM, two_stage ? nullptr : out);
        if (two_stage)
            snn_expand<<<1024, 256, 0, stream>>>(spM, out);
    }
}